// Round 11
// baseline (702.734 us; speedup 1.0000x reference)
//
#include <hip/hip_runtime.h>

#define N_NODES 50000
#define N_EDGES 800000
#define DIM 256
#define NG 64
#define EPS_BN 1e-5f
#define NB_AGG 3125
#define NB_COL 512
#define NSPLIT 32
// prep mega-kernel block ranges
#define PB_CNT 3125
#define PB_BND 196
#define PB_CVT 896
#define PB_CST 512
#define PB_TOTAL (PB_CNT + PB_BND + PB_CVT + PB_CST)

typedef _Float16 f16;
typedef _Float16 half8 __attribute__((ext_vector_type(8)));
typedef _Float16 half4 __attribute__((ext_vector_type(4)));
typedef float floatx4 __attribute__((ext_vector_type(4)));

__device__ __forceinline__ int fkey(float f) { int i = __float_as_int(f); return (i >= 0) ? i : (i ^ 0x7fffffff); }
__device__ __forceinline__ float keyf(int k) { return __int_as_float((k >= 0) ? k : (k ^ 0x7fffffff)); }

// ============ prep mega-kernel: histogram+lpos | graph bounds | weight convert | input col_stats ============
__global__ __launch_bounds__(256) void prep_kernel(const int* __restrict__ dst, int* __restrict__ cnt,
                                                   int* __restrict__ lpos,
                                                   const int* __restrict__ batch, int* __restrict__ start,
                                                   const float* __restrict__ W0, const float* __restrict__ W1,
                                                   const float* __restrict__ W2, const float* __restrict__ Wa1,
                                                   f16* __restrict__ T0, f16* __restrict__ T1,
                                                   f16* __restrict__ T2, f16* __restrict__ T3,
                                                   const float* __restrict__ X, float* __restrict__ part) {
    int gb = blockIdx.x;
    int tid = threadIdx.x;
    if (gb < PB_CNT) {
        for (int i = gb * 256 + tid; i < N_EDGES; i += PB_CNT * 256)
            lpos[i] = atomicAdd(&cnt[dst[i]], 1);
    } else if (gb < PB_CNT + PB_BND) {
        int i = (gb - PB_CNT) * 256 + tid;
        if (i < N_NODES) {
            int b = batch[i];
            if (i == 0 || batch[i - 1] != b) start[b] = i + 1;   // 0 = absent
        }
    } else if (gb < PB_CNT + PB_BND + PB_CVT) {
        int idx = (gb - PB_CNT - PB_BND) * 256 + tid;
        if (idx < 196608) {
            int w = idx >> 16, r = idx & 65535;
            const float* W = (w == 0) ? W0 : (w == 1) ? W1 : W2;
            f16* T = (w == 0) ? T0 : (w == 1) ? T1 : T2;
            int m = r >> 8, k = r & 255;
            T[r] = (f16)W[(size_t)k * 256 + m];
        } else {
            int r = idx - 196608;
            int m = r >> 8, k = r & 255;
            T3[r] = (f16)Wa1[(size_t)k * 128 + m];
        }
    } else {
        int blk = gb - (PB_CNT + PB_BND + PB_CVT);   // 0..511
        int c = tid;
        float s = 0.f, q = 0.f;
        for (int i = blk; i < N_NODES; i += PB_CST) {
            float v = X[(size_t)i * DIM + c];
            s += v; q += v * v;
        }
        part[(size_t)blk * 512 + c] = s;
        part[(size_t)blk * 512 + DIM + c] = q;
    }
}

// ============ merged level-1 reduce + (last block) finalize -> affine A[c]=rstd*g, B[c]=b-mean*A ============
__global__ __launch_bounds__(256) void reduce_finalize_kernel(const float* __restrict__ part, int nrows,
                                                              float* __restrict__ p2, int* __restrict__ counter,
                                                              const float* __restrict__ g, const float* __restrict__ b,
                                                              float* __restrict__ affine, float inv_n) {
    int col = blockIdx.x * 256 + threadIdx.x;
    int chunk = (nrows + NSPLIT - 1) / NSPLIT;
    int r0 = blockIdx.y * chunk;
    int r1 = min(r0 + chunk, nrows);
    float t = 0.f;
    for (int r = r0; r < r1; r++) t += part[(size_t)r * 512 + col];
    p2[(size_t)blockIdx.y * 512 + col] = t;
    __threadfence();
    __shared__ int lastf;
    if (threadIdx.x == 0) lastf = (atomicAdd(counter, 1) == 2 * NSPLIT - 1) ? 1 : 0;
    __syncthreads();
    if (lastf) {
        __threadfence();
        int c = threadIdx.x;
        float s = 0.f, q = 0.f;
#pragma unroll
        for (int r = 0; r < NSPLIT; r++) {
            s += p2[(size_t)r * 512 + c];
            q += p2[(size_t)r * 512 + DIM + c];
        }
        float m = s * inv_n;
        float v = q * inv_n - m * m;
        float rstd = rsqrtf(v + EPS_BN);
        float A = rstd * g[c];
        affine[c] = A;
        affine[DIM + c] = b[c] - m * A;
    }
}

// ============ single-dispatch chained scan (25 blocks): prefix + dinv ============
#define SCHUNK 2048
__global__ __launch_bounds__(256) void scan_kernel(const int* __restrict__ cnt, int n,
                                                   int* __restrict__ outp, int* __restrict__ chain,
                                                   float* __restrict__ dinv) {
    __shared__ int lds[256];
    __shared__ int sprefix;
    int t = threadIdx.x;
    int b = blockIdx.x;
    int base = b * SCHUNK + t * 8;
    int v[8]; int s = 0;
#pragma unroll
    for (int j = 0; j < 8; j++) {
        int id = base + j;
        int x = 0;
        if (id < n) { x = cnt[id]; dinv[id] = rsqrtf((float)x + 1.0f); }
        v[j] = s; s += x;
    }
    lds[t] = s; __syncthreads();
    for (int o = 1; o < 256; o <<= 1) {
        int add = (t >= o) ? lds[t - o] : 0;
        __syncthreads();
        lds[t] += add;
        __syncthreads();
    }
    int excl = lds[t] - s;
    int total = lds[255];
    if (t == 0) {
        int pref = 0;
        if (b > 0) {
            int p;
            do { p = atomicAdd(&chain[b - 1], 0); } while (p == 0);
            pref = p - 1;
        }
        atomicExch(&chain[b], pref + total + 1);
        sprefix = pref;
    }
    __syncthreads();
    int pref = sprefix;
#pragma unroll
    for (int j = 0; j < 8; j++) { int id = base + j; if (id < n) outp[id] = pref + excl + v[j]; }
    if (b == gridDim.x - 1 && t == 0) outp[n] = pref + total;
}

// ============ atomic-free scatter + (extra block) graph offsets + maxkey init ============
__global__ void scatter_offsets_kernel(const int* __restrict__ src, const int* __restrict__ dst,
                                       const int* __restrict__ lpos, int ne,
                                       const int* __restrict__ rowp, int* __restrict__ ss,
                                       const int* __restrict__ start, int* __restrict__ off,
                                       int* __restrict__ cnt, int* __restrict__ maxkey) {
    if (blockIdx.x == NB_AGG) {
        if (threadIdx.x == 0) {
            int nxt = N_NODES;
            for (int g = NG - 1; g >= 0; --g) {
                int s = start[g];
                int o = (s == 0) ? nxt : (s - 1);
                off[g] = o;
                cnt[g] = nxt - o;
                nxt = o;
            }
            maxkey[0] = 0x80000000;
        }
        return;
    }
    for (int e = blockIdx.x * blockDim.x + threadIdx.x; e < ne; e += NB_AGG * 256)
        ss[rowp[dst[e]] + lpos[e]] = src[e];
}

// ============================ GCN edge aggregation (full-row half4 gather) ============================
__global__ __launch_bounds__(256) void gcn_agg_kernel(const f16* __restrict__ h, const int* __restrict__ rowp,
                                                      const int* __restrict__ ss, const float* __restrict__ dinv,
                                                      const float* __restrict__ bias, f16* __restrict__ out,
                                                      float* __restrict__ part, int n) {
    int wave = threadIdx.x >> 6;
    int lane = threadIdx.x & 63;
    int c = lane * 4;
    float4 bv = *(const float4*)&bias[c];
    float s0a = 0.f, s1a = 0.f, s2a = 0.f, s3a = 0.f;
    float q0a = 0.f, q1a = 0.f, q2a = 0.f, q3a = 0.f;
    for (int row = blockIdx.x * 4 + wave; row < n; row += gridDim.x * 4) {
        float ax = 0.f, ay = 0.f, az = 0.f, aw = 0.f;
        int e0 = rowp[row], e1 = rowp[row + 1];
        int e = e0;
        for (; e + 3 < e1; e += 4) {
            int i0 = ss[e], i1 = ss[e + 1], i2 = ss[e + 2], i3 = ss[e + 3];
            half4 h0 = *(const half4*)&h[((size_t)i0 << 8) + c];
            half4 h1 = *(const half4*)&h[((size_t)i1 << 8) + c];
            half4 h2 = *(const half4*)&h[((size_t)i2 << 8) + c];
            half4 h3 = *(const half4*)&h[((size_t)i3 << 8) + c];
            ax += ((float)h0[0] + (float)h1[0]) + ((float)h2[0] + (float)h3[0]);
            ay += ((float)h0[1] + (float)h1[1]) + ((float)h2[1] + (float)h3[1]);
            az += ((float)h0[2] + (float)h1[2]) + ((float)h2[2] + (float)h3[2]);
            aw += ((float)h0[3] + (float)h1[3]) + ((float)h2[3] + (float)h3[3]);
        }
        for (; e < e1; e++) {
            int si = ss[e];
            half4 hv = *(const half4*)&h[((size_t)si << 8) + c];
            ax += (float)hv[0]; ay += (float)hv[1]; az += (float)hv[2]; aw += (float)hv[3];
        }
        float di = dinv[row];
        half4 hs = *(const half4*)&h[((size_t)row << 8) + c];
        float rx = di * (ax + (float)hs[0]) + bv.x;
        float ry = di * (ay + (float)hs[1]) + bv.y;
        float rz = di * (az + (float)hs[2]) + bv.z;
        float rw = di * (aw + (float)hs[3]) + bv.w;
        half4 o; o[0] = (f16)rx; o[1] = (f16)ry; o[2] = (f16)rz; o[3] = (f16)rw;
        *(half4*)&out[((size_t)row << 8) + c] = o;
        float t;
        t = fmaxf(rx, 0.f); s0a += t; q0a += t * t;
        t = fmaxf(ry, 0.f); s1a += t; q1a += t * t;
        t = fmaxf(rz, 0.f); s2a += t; q2a += t * t;
        t = fmaxf(rw, 0.f); s3a += t; q3a += t * t;
    }
    __shared__ float sred[4][64][4];
    __shared__ float qred[4][64][4];
    sred[wave][lane][0] = s0a; sred[wave][lane][1] = s1a; sred[wave][lane][2] = s2a; sred[wave][lane][3] = s3a;
    qred[wave][lane][0] = q0a; qred[wave][lane][1] = q1a; qred[wave][lane][2] = q2a; qred[wave][lane][3] = q3a;
    __syncthreads();
    if (wave == 0) {
        size_t base = (size_t)blockIdx.x * 512;
        float4 a = make_float4(0.f, 0.f, 0.f, 0.f), qv = make_float4(0.f, 0.f, 0.f, 0.f);
#pragma unroll
        for (int ww = 0; ww < 4; ww++) {
            a.x += sred[ww][lane][0]; a.y += sred[ww][lane][1]; a.z += sred[ww][lane][2]; a.w += sred[ww][lane][3];
            qv.x += qred[ww][lane][0]; qv.y += qred[ww][lane][1]; qv.z += qred[ww][lane][2]; qv.w += qred[ww][lane][3];
        }
        *(float4*)&part[base + c] = a;
        *(float4*)&part[base + DIM + c] = qv;
    }
}

// ============================ fused BN + MFMA GEMM, BN=256 (full M, single column block) ============================
#define BM 128
#define BK 32
#define LDP 40
__global__ __launch_bounds__(256) void gemm_fused_kernel(const float* __restrict__ Xf32, const f16* __restrict__ Ch,
                                                         const f16* __restrict__ Aold, f16* __restrict__ Afout,
                                                         const float* __restrict__ affine,
                                                         const f16* __restrict__ Wt, f16* __restrict__ Cout,
                                                         const float* __restrict__ scale, int n, int K) {
    __shared__ __align__(16) f16 As[BM * LDP];
    __shared__ __align__(16) f16 Bs[256 * LDP];
    __shared__ float sA[256], sB[256];
    int tid = threadIdx.x;
    sA[tid] = affine[tid]; sB[tid] = affine[256 + tid];
    int wave = tid >> 6, lane = tid & 63;
    int wm = wave >> 1, wn = wave & 1;
    int q = lane >> 4, l16 = lane & 15;
    int bm = blockIdx.x * BM;
    int kc = (tid & 3) * 8;
    int writer = (Afout != nullptr);
    floatx4 acc[4][8] = {};
    __syncthreads();
    for (int k0 = 0; k0 < K; k0 += BK) {
        float a8[8], b8[8];
#pragma unroll
        for (int j = 0; j < 8; j++) { a8[j] = sA[k0 + kc + j]; b8[j] = sB[k0 + kc + j]; }
        // stage A (128 rows x 32 halves): 2 rounds
#pragma unroll
        for (int rr = 0; rr < 2; rr++) {
            int cidx = tid + rr * 256;
            int row = cidx >> 2;
            int arow = bm + row; if (arow >= n) arow = n - 1;
            float v[8];
            if (Xf32) {
                float4 x0 = *(const float4*)&Xf32[(size_t)arow * K + k0 + kc];
                float4 x1 = *(const float4*)&Xf32[(size_t)arow * K + k0 + kc + 4];
                v[0] = x0.x; v[1] = x0.y; v[2] = x0.z; v[3] = x0.w;
                v[4] = x1.x; v[5] = x1.y; v[6] = x1.z; v[7] = x1.w;
            } else {
                half8 ch = *(const half8*)&Ch[(size_t)arow * K + k0 + kc];
#pragma unroll
                for (int j = 0; j < 8; j++) v[j] = fmaxf((float)ch[j], 0.f);
            }
            half8 af;
            if (Aold) {
                half8 ao = *(const half8*)&Aold[(size_t)arow * K + k0 + kc];
#pragma unroll
                for (int j = 0; j < 8; j++) af[j] = (f16)(v[j] * a8[j] + b8[j] + (float)ao[j]);
            } else {
#pragma unroll
                for (int j = 0; j < 8; j++) af[j] = (f16)(v[j] * a8[j] + b8[j]);
            }
            *(float4*)&As[row * LDP + kc] = *(float4*)&af;
            if (writer && bm + row < n) *(half8*)&Afout[(size_t)arow * K + k0 + kc] = af;
        }
        // stage B (256 rows x 32 halves): 4 rounds
#pragma unroll
        for (int rr = 0; rr < 4; rr++) {
            int cidx = tid + rr * 256;
            int row = cidx >> 2;                 // 0..255
            *(float4*)&Bs[row * LDP + kc] = *(const float4*)&Wt[(size_t)row * K + k0 + kc];
        }
        __syncthreads();
        half8 afr[4], bfr[8];
#pragma unroll
        for (int i = 0; i < 4; i++) afr[i] = *(half8*)&As[(wm * 64 + i * 16 + l16) * LDP + q * 8];
#pragma unroll
        for (int j = 0; j < 8; j++) bfr[j] = *(half8*)&Bs[(wn * 128 + j * 16 + l16) * LDP + q * 8];
#pragma unroll
        for (int i = 0; i < 4; i++)
#pragma unroll
            for (int j = 0; j < 8; j++)
                acc[i][j] = __builtin_amdgcn_mfma_f32_16x16x32_f16(afr[i], bfr[j], acc[i][j], 0, 0, 0);
        __syncthreads();
    }
#pragma unroll
    for (int i = 0; i < 4; i++) {
#pragma unroll
        for (int r = 0; r < 4; r++) {
            int row = bm + wm * 64 + i * 16 + q * 4 + r;
            if (row < n) {
                float sc = scale[row];
#pragma unroll
                for (int j = 0; j < 8; j++) {
                    int col = wn * 128 + j * 16 + l16;
                    Cout[(size_t)row * 256 + col] = (f16)(acc[i][j][r] * sc);
                }
            }
        }
    }
}

// ============ attention GEMM: fused BN staging + leaky+Wa2 epilogue + atomicMax, writes Af ============
__global__ __launch_bounds__(256) void gemm_attn_kernel(const f16* __restrict__ Ch, const f16* __restrict__ Aold,
                                                        f16* __restrict__ Afout, const float* __restrict__ affine,
                                                        const f16* __restrict__ Wt,
                                                        const float* __restrict__ ba1, const float* __restrict__ Wa2,
                                                        const float* __restrict__ ba2, float* __restrict__ score,
                                                        int* __restrict__ maxkey, int n, int K) {
    __shared__ __align__(16) f16 As[BM * LDP];
    __shared__ __align__(16) f16 Bs[128 * LDP];
    __shared__ float sA[256], sB[256];
    __shared__ float scred[128][2];
    int tid = threadIdx.x;
    sA[tid] = affine[tid]; sB[tid] = affine[256 + tid];
    int wave = tid >> 6, lane = tid & 63;
    int wm = wave >> 1, wn = wave & 1;
    int q = lane >> 4, l16 = lane & 15;
    int bm = blockIdx.x * BM;
    int kc = (tid & 3) * 8;
    floatx4 acc[4][4] = {};
    __syncthreads();
    for (int k0 = 0; k0 < K; k0 += BK) {
        float a8[8], b8[8];
#pragma unroll
        for (int j = 0; j < 8; j++) { a8[j] = sA[k0 + kc + j]; b8[j] = sB[k0 + kc + j]; }
#pragma unroll
        for (int rr = 0; rr < 2; rr++) {
            int cidx = tid + rr * 256;
            int row = cidx >> 2;
            int arow = bm + row; if (arow >= n) arow = n - 1;
            half8 ch = *(const half8*)&Ch[(size_t)arow * K + k0 + kc];
            half8 ao = *(const half8*)&Aold[(size_t)arow * K + k0 + kc];
            half8 af;
#pragma unroll
            for (int j = 0; j < 8; j++)
                af[j] = (f16)(fmaxf((float)ch[j], 0.f) * a8[j] + b8[j] + (float)ao[j]);
            *(float4*)&As[row * LDP + kc] = *(float4*)&af;
            if (bm + row < n) *(half8*)&Afout[(size_t)arow * K + k0 + kc] = af;
            *(float4*)&Bs[row * LDP + kc] = *(const float4*)&Wt[(size_t)row * K + k0 + kc];
        }
        __syncthreads();
        half8 afr[4], bfr[4];
#pragma unroll
        for (int i = 0; i < 4; i++) afr[i] = *(half8*)&As[(wm * 64 + i * 16 + l16) * LDP + q * 8];
#pragma unroll
        for (int j = 0; j < 4; j++) bfr[j] = *(half8*)&Bs[(wn * 64 + j * 16 + l16) * LDP + q * 8];
#pragma unroll
        for (int i = 0; i < 4; i++)
#pragma unroll
            for (int j = 0; j < 4; j++)
                acc[i][j] = __builtin_amdgcn_mfma_f32_16x16x32_f16(afr[i], bfr[j], acc[i][j], 0, 0, 0);
        __syncthreads();
    }
    float ba1v[4], wa2v[4];
#pragma unroll
    for (int j = 0; j < 4; j++) {
        int col = wn * 64 + j * 16 + l16;
        ba1v[j] = ba1[col];
        wa2v[j] = Wa2[col];
    }
#pragma unroll
    for (int i = 0; i < 4; i++)
#pragma unroll
        for (int r = 0; r < 4; r++) {
            float p = 0.f;
#pragma unroll
            for (int j = 0; j < 4; j++) {
                float v = acc[i][j][r] + ba1v[j];
                v = (v > 0.f) ? v : 0.01f * v;
                p += v * wa2v[j];
            }
#pragma unroll
            for (int o = 1; o < 16; o <<= 1) p += __shfl_xor(p, o);
            if (l16 == 0) scred[wm * 64 + i * 16 + q * 4 + r][wn] = p;
        }
    __syncthreads();
    __shared__ float mred[128];
    if (tid < 128) {
        int grow = bm + tid;
        float sc = scred[tid][0] + scred[tid][1] + ba2[0];
        if (grow < n) score[grow] = sc; else sc = -3.0e38f;
        mred[tid] = sc;
    }
    __syncthreads();
    for (int o = 64; o > 0; o >>= 1) {
        if (tid < o && tid + o < 128) mred[tid] = fmaxf(mred[tid], mred[tid + o]);
        __syncthreads();
    }
    if (tid == 0) atomicMax(maxkey, fkey(mred[0]));
}

// pooled[g,c] += striped sum of Af[i,c]*exp(score[i]-mx); also global sum-exp. grid (NG, 8)
__global__ __launch_bounds__(256) void pool_kernel(const f16* __restrict__ Af, const float* __restrict__ score,
                                                   const int* __restrict__ offs, const int* __restrict__ cnts,
                                                   const int* __restrict__ maxkey, float* __restrict__ expsum,
                                                   float* __restrict__ pooled) {
    float mx = keyf(maxkey[0]);
    int c = threadIdx.x;
    int g = blockIdx.x;
    int st = offs[g], cn = cnts[g];
    float acc = 0.f, esum = 0.f;
    for (int i = (int)blockIdx.y; i < cn; i += 32) {
        int i1 = i + 8, i2 = i + 16, i3 = i + 24;
        float s0 = score[st + i];
        float s1 = (i1 < cn) ? score[st + i1] : -3.0e38f;
        float s2 = (i2 < cn) ? score[st + i2] : -3.0e38f;
        float s3 = (i3 < cn) ? score[st + i3] : -3.0e38f;
        float e0 = expf(s0 - mx), e1 = expf(s1 - mx), e2 = expf(s2 - mx), e3 = expf(s3 - mx);
        float a0 = (float)Af[(size_t)(st + i) * DIM + c];
        float a1 = (i1 < cn) ? (float)Af[(size_t)(st + i1) * DIM + c] : 0.f;
        float a2 = (i2 < cn) ? (float)Af[(size_t)(st + i2) * DIM + c] : 0.f;
        float a3 = (i3 < cn) ? (float)Af[(size_t)(st + i3) * DIM + c] : 0.f;
        acc += a0 * e0 + a1 * e1 + a2 * e2 + a3 * e3;
        esum += (e0 + e1) + (e2 + e3);
    }
    atomicAdd(&pooled[g * DIM + c], acc);
    if (c == 0) atomicAdd(expsum, esum);
}

__global__ __launch_bounds__(256) void out_kernel(const float* __restrict__ pooled, const int* __restrict__ cnt,
                                                  const float* __restrict__ expsum, const float* __restrict__ Wo,
                                                  const float* __restrict__ bo, float* __restrict__ out) {
    __shared__ float l0[256], l1[256];
    int g = blockIdx.x, c = threadIdx.x;
    float scale = 1.f / (expsum[0] * fmaxf((float)cnt[g], 1.f));
    float v = pooled[g * DIM + c] * scale;
    l0[c] = v * Wo[c * 2];
    l1[c] = v * Wo[c * 2 + 1];
    __syncthreads();
    for (int o = 128; o > 0; o >>= 1) {
        if (c < o) { l0[c] += l0[c + o]; l1[c] += l1[c + o]; }
        __syncthreads();
    }
    if (c == 0) { out[g * 2] = l0[0] + bo[0]; out[g * 2 + 1] = l1[0] + bo[1]; }
}

// ============================ launch ============================
extern "C" void kernel_launch(void* const* d_in, const int* in_sizes, int n_in,
                              void* d_out, int out_size, void* d_ws, size_t ws_size,
                              hipStream_t stream) {
    const float* x       = (const float*)d_in[0];
    const int*   ei      = (const int*)d_in[1];
    const int*   batch   = (const int*)d_in[2];
    const float* bn_in_g = (const float*)d_in[3];
    const float* bn_in_b = (const float*)d_in[4];
    const float* Ws[3]   = {(const float*)d_in[5],  (const float*)d_in[9],  (const float*)d_in[13]};
    const float* bs[3]   = {(const float*)d_in[6],  (const float*)d_in[10], (const float*)d_in[14]};
    const float* gs[3]   = {(const float*)d_in[7],  (const float*)d_in[11], (const float*)d_in[15]};
    const float* bbs[3]  = {(const float*)d_in[8],  (const float*)d_in[12], (const float*)d_in[16]};
    const float* Wa1 = (const float*)d_in[17];
    const float* ba1 = (const float*)d_in[18];
    const float* Wa2 = (const float*)d_in[19];
    const float* ba2 = (const float*)d_in[20];
    const float* Wo  = (const float*)d_in[21];
    const float* bo  = (const float*)d_in[22];

    char* w = (char*)d_ws;
    size_t off = 0;
    auto alloc = [&](size_t bytes) -> void* {
        void* p = w + off;
        off += (bytes + 255) & ~(size_t)255;
        return p;
    };
    // --- zeroed region (single memset): deg, gstart, chain, pooled, counters, expsum ---
    int*   deg     = (int*)alloc((size_t)N_NODES * 4);
    int*   gstart  = (int*)alloc(64 * 4);                 // 0 = absent (start+1 convention)
    int*   chain   = (int*)alloc(32 * 4);                 // scan chain flags
    float* pooled  = (float*)alloc((size_t)NG * DIM * 4);
    int*   counters = (int*)alloc(4 * 4);
    float* expsum  = (float*)alloc(4);
    size_t zero_span = off;
    // --- rest ---
    float* stats_part = (float*)alloc((size_t)NB_AGG * 512 * 4);
    float* stats_p2   = (float*)alloc((size_t)NSPLIT * 512 * 4);
    float* affine  = (float*)alloc(512 * 4);
    f16*   AfA  = (f16*)alloc((size_t)N_NODES * DIM * 2);
    f16*   AfB  = (f16*)alloc((size_t)N_NODES * DIM * 2);
    f16*   Bh   = (f16*)alloc((size_t)N_NODES * DIM * 2);   // hscaled
    f16*   Chb  = (f16*)alloc((size_t)N_NODES * DIM * 2);   // aggregated pre-BN
    f16*   Wt[3];
    for (int l = 0; l < 3; l++) Wt[l] = (f16*)alloc((size_t)DIM * DIM * 2);
    f16*   Wa1t = (f16*)alloc((size_t)128 * DIM * 2);
    int* sorted_src = (int*)alloc((size_t)N_EDGES * 4);
    int* lpos   = (int*)alloc((size_t)N_EDGES * 4);
    float* dinv = (float*)alloc((size_t)N_NODES * 4);
    int* rowp   = (int*)alloc((size_t)(N_NODES + 1) * 4);
    float* score = (float*)alloc((size_t)N_NODES * 4);
    int* maxkey  = (int*)alloc(16);
    int* cnt_g   = (int*)alloc(64 * 4);
    int* off_g   = (int*)alloc(64 * 4);

    const int* src = ei;
    const int* dst = ei + N_EDGES;
    const int NSCAN = (N_NODES + SCHUNK - 1) / SCHUNK;
    const float inv_n = 1.f / N_NODES;

    hipMemsetAsync(d_ws, 0, zero_span, stream);

    // ---- prep mega-kernel: histogram+lpos | bounds | weight convert | input col_stats ----
    prep_kernel<<<PB_TOTAL, 256, 0, stream>>>(dst, deg, lpos, batch, gstart,
                                              Ws[0], Ws[1], Ws[2], Wa1, Wt[0], Wt[1], Wt[2], Wa1t,
                                              x, stats_part);
    // ---- single-dispatch chained scan (also dinv) ----
    scan_kernel<<<NSCAN, 256, 0, stream>>>(deg, N_NODES, rowp, chain, dinv);
    // ---- scatter + graph offsets ----
    scatter_offsets_kernel<<<NB_AGG + 1, 256, 0, stream>>>(src, dst, lpos, N_EDGES, rowp, sorted_src,
                                                           gstart, off_g, cnt_g, maxkey);
    // ---- input BN affine ----
    reduce_finalize_kernel<<<dim3(2, NSPLIT), 256, 0, stream>>>(stats_part, NB_COL, stats_p2, counters + 0,
                                                                bn_in_g, bn_in_b, affine, inv_n);

    // ---- GCN layers (BN fused into GEMM staging) ----
    const int NGB = (N_NODES + BM - 1) / BM;   // 391
    // layer 0
    gemm_fused_kernel<<<NGB, 256, 0, stream>>>(x, nullptr, nullptr, nullptr, affine, Wt[0], Bh, dinv, N_NODES, DIM);
    gcn_agg_kernel<<<NB_AGG, 256, 0, stream>>>(Bh, rowp, sorted_src, dinv, bs[0], Chb, stats_part, N_NODES);
    reduce_finalize_kernel<<<dim3(2, NSPLIT), 256, 0, stream>>>(stats_part, NB_AGG, stats_p2, counters + 1,
                                                                gs[0], bbs[0], affine, inv_n);
    // layer 1
    gemm_fused_kernel<<<NGB, 256, 0, stream>>>(nullptr, Chb, nullptr, AfA, affine, Wt[1], Bh, dinv, N_NODES, DIM);
    gcn_agg_kernel<<<NB_AGG, 256, 0, stream>>>(Bh, rowp, sorted_src, dinv, bs[1], Chb, stats_part, N_NODES);
    reduce_finalize_kernel<<<dim3(2, NSPLIT), 256, 0, stream>>>(stats_part, NB_AGG, stats_p2, counters + 2,
                                                                gs[1], bbs[1], affine, inv_n);
    // layer 2
    gemm_fused_kernel<<<NGB, 256, 0, stream>>>(nullptr, Chb, AfA, AfB, affine, Wt[2], Bh, dinv, N_NODES, DIM);
    gcn_agg_kernel<<<NB_AGG, 256, 0, stream>>>(Bh, rowp, sorted_src, dinv, bs[2], Chb, stats_part, N_NODES);
    reduce_finalize_kernel<<<dim3(2, NSPLIT), 256, 0, stream>>>(stats_part, NB_AGG, stats_p2, counters + 3,
                                                                gs[2], bbs[2], affine, inv_n);

    // ---- attention ----
    gemm_attn_kernel<<<NGB, 256, 0, stream>>>(Chb, AfB, AfA, affine, Wa1t,
                                              ba1, Wa2, ba2, score, maxkey, N_NODES, DIM);

    // ---- pooling + output ----
    pool_kernel<<<dim3(NG, 8), 256, 0, stream>>>(AfA, score, off_g, cnt_g, maxkey, expsum, pooled);
    out_kernel<<<NG, 256, 0, stream>>>(pooled, cnt_g, expsum, Wo, bo, (float*)d_out);
}